// Round 4
// baseline (529.846 us; speedup 1.0000x reference)
//
#include <hip/hip_runtime.h>
#include <stdint.h>

typedef unsigned short u16;
typedef __attribute__((ext_vector_type(8))) _Float16 half8;  // 8 x f16 (4 VGPRs)
typedef __attribute__((ext_vector_type(4))) float f32x4;

#define L2E 1.4426950408889634f

// B=4, T=2048, D=512, H=8, DK=64; NTOK = B*T = 8192
#define NTOK 8192
#define DIM  512
#define TT   2048

__device__ __forceinline__ u16 f2h(float f) {
  _Float16 h = (_Float16)f;  // RNE via v_cvt_f16_f32
  return __builtin_bit_cast(u16, h);
}

__device__ __forceinline__ void async16(const void* g, void* l) {
  __builtin_amdgcn_global_load_lds(
      (const __attribute__((address_space(1))) unsigned int*)g,
      (__attribute__((address_space(3))) unsigned int*)l, 16, 0, 0);
}

// ---------------- fp32 -> fp16 conversion: x (4.19M) + 4 weights (262144 each)
__global__ __launch_bounds__(256) void k_convert(
    const float* __restrict__ x, const float* __restrict__ wq,
    const float* __restrict__ wk, const float* __restrict__ wv,
    const float* __restrict__ wo, u16* __restrict__ xb) {
  size_t i = ((size_t)blockIdx.x * 256 + threadIdx.x) * 8;
  const float* src;
  u16* dst;
  size_t off;
  if (i < 4194304) {
    src = x; dst = xb; off = i;
  } else {
    size_t j = i - 4194304;
    int w = (int)(j >> 18);
    off = j & 262143;
    src = (w == 0) ? wq : (w == 1) ? wk : (w == 2) ? wv : wo;
    dst = xb + 4194304 + (size_t)w * 262144;
  }
  float4 a = *(const float4*)(src + off);
  float4 b = *(const float4*)(src + off + 4);
  uint4 pk;
  pk.x = (unsigned)f2h(a.x) | ((unsigned)f2h(a.y) << 16);
  pk.y = (unsigned)f2h(a.z) | ((unsigned)f2h(a.w) << 16);
  pk.z = (unsigned)f2h(b.x) | ((unsigned)f2h(b.y) << 16);
  pk.w = (unsigned)f2h(b.z) | ((unsigned)f2h(b.w) << 16);
  *(uint4*)(dst + off) = pk;
}

// ---------------- merged QKV projection: grid (64, 12), 128x128 tiles
// n-tiles span stacked [Wq;Wk;Wv] (1536 rows). z = n0/512 selects output.
// z<2 (Q,K): head-major [bh][t][dk]. z==2 (V): swapped MFMA operands ->
// transposed Vt [bh][dk][t] with coalesced stores.
__global__ __launch_bounds__(256) void k_proj(
    const u16* __restrict__ A, const u16* __restrict__ Wall,
    u16* __restrict__ Db) {
  const int tid = threadIdx.x;
  const int wave = tid >> 6, lane = tid & 63;
  const int quad = lane >> 4, l16 = lane & 15;
  const int wr = wave >> 1, wc = wave & 1;
  const int m0 = blockIdx.x * 128;
  const int n0g = blockIdx.y * 128;      // 0..1536
  const int z = n0g >> 9;                // 0,1,2 (block-uniform)
  const int n0 = n0g & 511;

  const u16* W = Wall + (size_t)n0g * DIM;
  u16* D = Db + (size_t)z * 4194304;

  __shared__ __align__(16) u16 As[128 * 64];
  __shared__ __align__(16) u16 Bs[128 * 64];

  f32x4 acc[4][4];
  for (int rt = 0; rt < 4; ++rt)
    for (int ct = 0; ct < 4; ++ct) acc[rt][ct] = (f32x4){0.f, 0.f, 0.f, 0.f};

  for (int kb = 0; kb < 8; ++kb) {
    const int k0 = kb * 64;
    for (int r = 0; r < 4; ++r) {
      int cid = r * 256 + tid;
      int row = cid >> 3, cl = cid & 7, cg = cl ^ (row & 7);
      async16(A + (size_t)(m0 + row) * DIM + k0 + cg * 8,
              &As[(r * 256 + wave * 64) * 8]);
    }
    for (int r = 0; r < 4; ++r) {
      int cid = r * 256 + tid;
      int row = cid >> 3, cl = cid & 7, cg = cl ^ (row & 7);
      async16(W + (size_t)row * DIM + k0 + cg * 8,
              &Bs[(r * 256 + wave * 64) * 8]);
    }
    __syncthreads();
    for (int kc = 0; kc < 2; ++kc) {
      half8 af[4], wf[4];
      for (int rt = 0; rt < 4; ++rt) {
        int row = wr * 64 + rt * 16 + l16;
        int c = (kc * 4 + quad) ^ (row & 7);
        af[rt] = *(const half8*)&As[row * 64 + c * 8];
      }
      for (int ct = 0; ct < 4; ++ct) {
        int row = wc * 64 + ct * 16 + l16;
        int c = (kc * 4 + quad) ^ (row & 7);
        wf[ct] = *(const half8*)&Bs[row * 64 + c * 8];
      }
      if (z != 2) {
        for (int rt = 0; rt < 4; ++rt)
          for (int ct = 0; ct < 4; ++ct)
            acc[rt][ct] = __builtin_amdgcn_mfma_f32_16x16x32_f16(
                af[rt], wf[ct], acc[rt][ct], 0, 0, 0);
      } else {
        for (int rt = 0; rt < 4; ++rt)
          for (int ct = 0; ct < 4; ++ct)
            acc[rt][ct] = __builtin_amdgcn_mfma_f32_16x16x32_f16(
                wf[ct], af[rt], acc[rt][ct], 0, 0, 0);
      }
    }
    __syncthreads();
  }

  // C/D layout: col = lane&15, row = quad*4 + reg.
  for (int rt = 0; rt < 4; ++rt)
    for (int ct = 0; ct < 4; ++ct)
      for (int reg = 0; reg < 4; ++reg) {
        float v = acc[rt][ct][reg];
        if (z != 2) {
          int gm = m0 + wr * 64 + rt * 16 + quad * 4 + reg;  // token
          int gn = n0 + wc * 64 + ct * 16 + l16;             // feature
          int bb = gm >> 11, t = gm & 2047, hh = gn >> 6, dk = gn & 63;
          D[(((size_t)(bb * 8 + hh) * TT + t) << 6) + dk] = f2h(v);
        } else {
          int feat = n0 + wc * 64 + ct * 16 + quad * 4 + reg;
          int tok  = m0 + wr * 64 + rt * 16 + l16;
          int bb = tok >> 11, t = tok & 2047, hh = feat >> 6, dk = feat & 63;
          D[(((size_t)(bb * 8 + hh) << 6) + dk) * TT + t] = f2h(v);
        }
      }
}

// ---------------- output GEMM: out = y @ Wo^T, 64x128 tiles, fp32 out
__global__ __launch_bounds__(256) void k_ogemm(
    const u16* __restrict__ A, const u16* __restrict__ W,
    float* __restrict__ Df) {
  const int tid = threadIdx.x;
  const int wave = tid >> 6, lane = tid & 63;
  const int quad = lane >> 4, l16 = lane & 15;
  const int wr = wave >> 1, wc = wave & 1;
  const int m0 = blockIdx.x * 64, n0 = blockIdx.y * 128;

  __shared__ __align__(16) u16 As[64 * 64];
  __shared__ __align__(16) u16 Bs[128 * 64];

  f32x4 acc[2][4];
  for (int rt = 0; rt < 2; ++rt)
    for (int ct = 0; ct < 4; ++ct) acc[rt][ct] = (f32x4){0.f, 0.f, 0.f, 0.f};

  for (int kb = 0; kb < 8; ++kb) {
    const int k0 = kb * 64;
    for (int r = 0; r < 2; ++r) {
      int cid = r * 256 + tid;
      int row = cid >> 3, cl = cid & 7, cg = cl ^ (row & 7);
      async16(A + (size_t)(m0 + row) * DIM + k0 + cg * 8,
              &As[(r * 256 + wave * 64) * 8]);
    }
    for (int r = 0; r < 4; ++r) {
      int cid = r * 256 + tid;
      int row = cid >> 3, cl = cid & 7, cg = cl ^ (row & 7);
      async16(W + (size_t)(n0 + row) * DIM + k0 + cg * 8,
              &Bs[(r * 256 + wave * 64) * 8]);
    }
    __syncthreads();
    for (int kc = 0; kc < 2; ++kc) {
      half8 af[2], wf[4];
      for (int rt = 0; rt < 2; ++rt) {
        int row = wr * 32 + rt * 16 + l16;
        int c = (kc * 4 + quad) ^ (row & 7);
        af[rt] = *(const half8*)&As[row * 64 + c * 8];
      }
      for (int ct = 0; ct < 4; ++ct) {
        int row = wc * 64 + ct * 16 + l16;
        int c = (kc * 4 + quad) ^ (row & 7);
        wf[ct] = *(const half8*)&Bs[row * 64 + c * 8];
      }
      for (int rt = 0; rt < 2; ++rt)
        for (int ct = 0; ct < 4; ++ct)
          acc[rt][ct] = __builtin_amdgcn_mfma_f32_16x16x32_f16(
              af[rt], wf[ct], acc[rt][ct], 0, 0, 0);
    }
    __syncthreads();
  }

  for (int rt = 0; rt < 2; ++rt)
    for (int ct = 0; ct < 4; ++ct)
      for (int reg = 0; reg < 4; ++reg) {
        int gm = m0 + wr * 32 + rt * 16 + quad * 4 + reg;
        int gn = n0 + wc * 64 + ct * 16 + l16;
        Df[(size_t)gm * DIM + gn] = acc[rt][ct][reg];
      }
}

// ---------------- flash attention, software-pipelined
// bx = ((h*32+qt)<<2)|b : 4 consecutive blocks share one bias tile (LLC reuse)
__global__ __launch_bounds__(256) void k_attn(
    const u16* __restrict__ Q, const u16* __restrict__ K,
    const u16* __restrict__ Vt, const float* __restrict__ bias,
    const float* __restrict__ mask, u16* __restrict__ Y) {
  const int tid = threadIdx.x;
  const int wv = tid >> 6;
  const int lane = tid & 63;
  const int quad = lane >> 4;
  const int l16 = lane & 15;

  const int bx = blockIdx.x;
  const int b = bx & 3;
  const int rest = bx >> 2;   // 0..255
  const int h = rest >> 5;    // 0..7
  const int qt = rest & 31;   // 0..31
  const int bh = b * 8 + h;
  const int q0 = qt * 64;

  __shared__ __align__(16) u16 Ks[2][64 * 64];  // K tile [s][dk], double-buffered
  __shared__ __align__(16) u16 Vs[2][64 * 64];  // V^T tile [dk][s], double-buffered
  __shared__ __align__(16) u16 Pl[64 * 72];     // P, padded stride 72

  // Q fragments (A-operand: m=lane&15, k=quad*8+j); wave wv owns rows wv*16..+15
  half8 qf[2];
  {
    size_t qrow = (size_t)bh * TT + q0 + wv * 16 + l16;
    for (int kc = 0; kc < 2; ++kc)
      qf[kc] = *(const half8*)(Q + qrow * 64 + kc * 32 + quad * 8);
  }

  // Per-lane bias row pointers (4 C-layout rows) and mask pointer.
  const int tg = q0 + wv * 16 + quad * 4;
  const float* bb0 = bias + (size_t)h * TT * TT + (size_t)tg * TT + l16;
  const float* mbase = mask + (size_t)b * TT + l16;

  float m_i[4], l_i[4];
  f32x4 oacc[4];
  for (int r = 0; r < 4; ++r) { m_i[r] = -1e30f; l_i[r] = 0.f; }
  for (int ct = 0; ct < 4; ++ct) oacc[ct] = (f32x4){0.f, 0.f, 0.f, 0.f};

  float bv[2][4][4];  // [slot][ct][reg]
  float mk[2][4];

  // Prologue: stage tile 0 (K/V -> LDS buf0, bias/mask -> regs slot0).
  {
    for (int r = 0; r < 2; ++r) {
      int cid = r * 256 + tid;
      int row = cid >> 3, cl = cid & 7, cg = cl ^ (row & 7);
      async16(K + ((size_t)bh * TT + row) * 64 + cg * 8,
              &Ks[0][(r * 256 + wv * 64) * 8]);
      async16(Vt + ((size_t)(bh * 64 + row)) * TT + cg * 8,
              &Vs[0][(r * 256 + wv * 64) * 8]);
    }
    for (int reg = 0; reg < 4; ++reg)
      for (int ct = 0; ct < 4; ++ct)
        bv[0][ct][reg] = bb0[(size_t)reg * TT + ct * 16];
    for (int ct = 0; ct < 4; ++ct) mk[0][ct] = mbase[ct * 16];
  }
  __syncthreads();

  for (int st = 0; st < 32; ++st) {
    const int cur = st & 1;
    // Prefetch tile st+1 (issued a full compute-phase before the waitcnt).
    if (st < 31) {
      const int nxt = cur ^ 1;
      const int s1 = (st + 1) * 64;
      for (int r = 0; r < 2; ++r) {
        int cid = r * 256 + tid;
        int row = cid >> 3, cl = cid & 7, cg = cl ^ (row & 7);
        async16(K + ((size_t)bh * TT + s1 + row) * 64 + cg * 8,
                &Ks[nxt][(r * 256 + wv * 64) * 8]);
        async16(Vt + ((size_t)(bh * 64 + row)) * TT + s1 + cg * 8,
                &Vs[nxt][(r * 256 + wv * 64) * 8]);
      }
      for (int reg = 0; reg < 4; ++reg)
        for (int ct = 0; ct < 4; ++ct)
          bv[nxt][ct][reg] = bb0[(size_t)reg * TT + s1 + ct * 16];
      for (int ct = 0; ct < 4; ++ct) mk[nxt][ct] = mbase[s1 + ct * 16];
    }

    // S = Q @ K^T from resident buffer.
    f32x4 sacc[4];
    for (int ct = 0; ct < 4; ++ct) sacc[ct] = (f32x4){0.f, 0.f, 0.f, 0.f};
    for (int kc = 0; kc < 2; ++kc) {
      half8 kf[4];
      for (int ct = 0; ct < 4; ++ct) {
        int row = ct * 16 + l16;
        int c = (kc * 4 + quad) ^ (row & 7);
        kf[ct] = *(const half8*)&Ks[cur][row * 64 + c * 8];
      }
      for (int ct = 0; ct < 4; ++ct)
        sacc[ct] = __builtin_amdgcn_mfma_f32_16x16x32_f16(
            qf[kc], kf[ct], sacc[ct], 0, 0, 0);
    }

    // Online softmax; each row lives in the 16 lanes of one quad.
    for (int reg = 0; reg < 4; ++reg) {
      float s[4];
      for (int ct = 0; ct < 4; ++ct)
        s[ct] = sacc[ct][reg] + bv[cur][ct][reg] + mk[cur][ct];
      float mx = fmaxf(fmaxf(s[0], s[1]), fmaxf(s[2], s[3]));
      mx = fmaxf(mx, __shfl_xor(mx, 1));
      mx = fmaxf(mx, __shfl_xor(mx, 2));
      mx = fmaxf(mx, __shfl_xor(mx, 4));
      mx = fmaxf(mx, __shfl_xor(mx, 8));
      float mold = m_i[reg];
      float mnew = fmaxf(mold, mx);
      float alpha = __builtin_amdgcn_exp2f((mold - mnew) * L2E);
      float p[4], rs = 0.f;
      for (int ct = 0; ct < 4; ++ct) {
        p[ct] = __builtin_amdgcn_exp2f((s[ct] - mnew) * L2E);
        rs += p[ct];
      }
      rs += __shfl_xor(rs, 1);
      rs += __shfl_xor(rs, 2);
      rs += __shfl_xor(rs, 4);
      rs += __shfl_xor(rs, 8);
      l_i[reg] = l_i[reg] * alpha + rs;
      m_i[reg] = mnew;
      for (int ct = 0; ct < 4; ++ct) oacc[ct][reg] *= alpha;
      int prow = wv * 16 + quad * 4 + reg;
      for (int ct = 0; ct < 4; ++ct) Pl[prow * 72 + ct * 16 + l16] = f2h(p[ct]);
    }
    __syncthreads();  // Pl visible (also drains prefetch vmcnt)

    // O += P @ V
    for (int kc = 0; kc < 2; ++kc) {
      half8 pf, vf[4];
      pf = *(const half8*)&Pl[(wv * 16 + l16) * 72 + kc * 32 + quad * 8];
      for (int ct = 0; ct < 4; ++ct) {
        int row = ct * 16 + l16;
        int c = (kc * 4 + quad) ^ (row & 7);
        vf[ct] = *(const half8*)&Vs[cur][row * 64 + c * 8];
      }
      for (int ct = 0; ct < 4; ++ct)
        oacc[ct] = __builtin_amdgcn_mfma_f32_16x16x32_f16(
            pf, vf[ct], oacc[ct], 0, 0, 0);
    }
    __syncthreads();  // protect Pl (and buffer swap) for next iteration
  }

  // Epilogue: y token-major [B,T,512] f16 (feeds the output GEMM).
  for (int reg = 0; reg < 4; ++reg) {
    int tgr = q0 + wv * 16 + quad * 4 + reg;
    float inv = 1.f / l_i[reg];
    for (int ct = 0; ct < 4; ++ct) {
      float v = oacc[ct][reg] * inv;
      Y[((size_t)(b * TT + tgr)) * DIM + h * 64 + ct * 16 + l16] = f2h(v);
    }
  }
}

extern "C" void kernel_launch(void* const* d_in, const int* in_sizes, int n_in,
                              void* d_out, int out_size, void* d_ws, size_t ws_size,
                              hipStream_t stream) {
  const float* x    = (const float*)d_in[0];
  const float* mask = (const float*)d_in[1];
  const float* bias = (const float*)d_in[2];
  const float* Wq   = (const float*)d_in[3];
  const float* Wk   = (const float*)d_in[4];
  const float* Wv   = (const float*)d_in[5];
  const float* Wo   = (const float*)d_in[6];
  (void)Wk; (void)Wv;  // consumed via contiguous weight block in ws

  // Workspace (f16 elems): xb | wq,wk,wv,wo | Q,K,Vt | y  (~44 MB)
  u16* xb  = (u16*)d_ws;
  u16* wb  = xb + 4194304;            // 4 * 262144
  u16* qkv = wb + 4 * 262144;         // Q, K head-major; V^T
  u16* yb  = qkv + 3 * (size_t)4194304;

  k_convert<<<2560, 256, 0, stream>>>(x, Wq, Wk, Wv, Wo, xb);
  k_proj<<<dim3(64, 12), 256, 0, stream>>>(xb, wb, qkv);
  k_attn<<<1024, 256, 0, stream>>>(qkv, qkv + 4194304,
                                   qkv + 2 * (size_t)4194304, bias, mask, yb);
  k_ogemm<<<dim3(128, 4), 256, 0, stream>>>(yb, wb + 3 * 262144, (float*)d_out);
}

// Round 5
// 499.349 us; speedup vs baseline: 1.0611x; 1.0611x over previous
//
#include <hip/hip_runtime.h>
#include <stdint.h>

typedef unsigned short u16;
typedef __attribute__((ext_vector_type(8))) _Float16 half8;  // 8 x f16 (4 VGPRs)
typedef __attribute__((ext_vector_type(4))) float f32x4;

#define L2E 1.4426950408889634f

// B=4, T=2048, D=512, H=8, DK=64; NTOK = B*T = 8192
#define NTOK 8192
#define DIM  512
#define TT   2048

__device__ __forceinline__ u16 f2h(float f) {
  _Float16 h = (_Float16)f;  // RNE via v_cvt_f16_f32
  return __builtin_bit_cast(u16, h);
}

__device__ __forceinline__ void async16(const void* g, void* l) {
  __builtin_amdgcn_global_load_lds(
      (const __attribute__((address_space(1))) unsigned int*)g,
      (__attribute__((address_space(3))) unsigned int*)l, 16, 0, 0);
}

// ---------------- fp32 -> fp16 conversion: x (4.19M) + 4 weights (262144 each)
__global__ __launch_bounds__(256) void k_convert(
    const float* __restrict__ x, const float* __restrict__ wq,
    const float* __restrict__ wk, const float* __restrict__ wv,
    const float* __restrict__ wo, u16* __restrict__ xb) {
  size_t i = ((size_t)blockIdx.x * 256 + threadIdx.x) * 8;
  const float* src;
  u16* dst;
  size_t off;
  if (i < 4194304) {
    src = x; dst = xb; off = i;
  } else {
    size_t j = i - 4194304;
    int w = (int)(j >> 18);
    off = j & 262143;
    src = (w == 0) ? wq : (w == 1) ? wk : (w == 2) ? wv : wo;
    dst = xb + 4194304 + (size_t)w * 262144;
  }
  float4 a = *(const float4*)(src + off);
  float4 b = *(const float4*)(src + off + 4);
  uint4 pk;
  pk.x = (unsigned)f2h(a.x) | ((unsigned)f2h(a.y) << 16);
  pk.y = (unsigned)f2h(a.z) | ((unsigned)f2h(a.w) << 16);
  pk.z = (unsigned)f2h(b.x) | ((unsigned)f2h(b.y) << 16);
  pk.w = (unsigned)f2h(b.z) | ((unsigned)f2h(b.w) << 16);
  *(uint4*)(dst + off) = pk;
}

// ---------------- merged QKV projection: grid (64, 12), 128x128 tiles
// n-tiles span stacked [Wq;Wk;Wv] (1536 rows). z = n0/512 selects output.
// z<2 (Q,K): head-major [bh][t][dk]. z==2 (V): swapped MFMA operands ->
// transposed Vt [bh][dk][t] with coalesced stores.
__global__ __launch_bounds__(256) void k_proj(
    const u16* __restrict__ A, const u16* __restrict__ Wall,
    u16* __restrict__ Db) {
  const int tid = threadIdx.x;
  const int wave = tid >> 6, lane = tid & 63;
  const int quad = lane >> 4, l16 = lane & 15;
  const int wr = wave >> 1, wc = wave & 1;
  const int m0 = blockIdx.x * 128;
  const int n0g = blockIdx.y * 128;      // 0..1536
  const int z = n0g >> 9;                // 0,1,2 (block-uniform)
  const int n0 = n0g & 511;

  const u16* W = Wall + (size_t)n0g * DIM;
  u16* D = Db + (size_t)z * 4194304;

  __shared__ __align__(16) u16 As[128 * 64];
  __shared__ __align__(16) u16 Bs[128 * 64];

  f32x4 acc[4][4];
  for (int rt = 0; rt < 4; ++rt)
    for (int ct = 0; ct < 4; ++ct) acc[rt][ct] = (f32x4){0.f, 0.f, 0.f, 0.f};

  for (int kb = 0; kb < 8; ++kb) {
    const int k0 = kb * 64;
    for (int r = 0; r < 4; ++r) {
      int cid = r * 256 + tid;
      int row = cid >> 3, cl = cid & 7, cg = cl ^ (row & 7);
      async16(A + (size_t)(m0 + row) * DIM + k0 + cg * 8,
              &As[(r * 256 + wave * 64) * 8]);
    }
    for (int r = 0; r < 4; ++r) {
      int cid = r * 256 + tid;
      int row = cid >> 3, cl = cid & 7, cg = cl ^ (row & 7);
      async16(W + (size_t)row * DIM + k0 + cg * 8,
              &Bs[(r * 256 + wave * 64) * 8]);
    }
    __syncthreads();
    for (int kc = 0; kc < 2; ++kc) {
      half8 af[4], wf[4];
      for (int rt = 0; rt < 4; ++rt) {
        int row = wr * 64 + rt * 16 + l16;
        int c = (kc * 4 + quad) ^ (row & 7);
        af[rt] = *(const half8*)&As[row * 64 + c * 8];
      }
      for (int ct = 0; ct < 4; ++ct) {
        int row = wc * 64 + ct * 16 + l16;
        int c = (kc * 4 + quad) ^ (row & 7);
        wf[ct] = *(const half8*)&Bs[row * 64 + c * 8];
      }
      if (z != 2) {
        for (int rt = 0; rt < 4; ++rt)
          for (int ct = 0; ct < 4; ++ct)
            acc[rt][ct] = __builtin_amdgcn_mfma_f32_16x16x32_f16(
                af[rt], wf[ct], acc[rt][ct], 0, 0, 0);
      } else {
        for (int rt = 0; rt < 4; ++rt)
          for (int ct = 0; ct < 4; ++ct)
            acc[rt][ct] = __builtin_amdgcn_mfma_f32_16x16x32_f16(
                wf[ct], af[rt], acc[rt][ct], 0, 0, 0);
      }
    }
    __syncthreads();
  }

  // C/D layout: col = lane&15, row = quad*4 + reg.
  for (int rt = 0; rt < 4; ++rt)
    for (int ct = 0; ct < 4; ++ct)
      for (int reg = 0; reg < 4; ++reg) {
        float v = acc[rt][ct][reg];
        if (z != 2) {
          int gm = m0 + wr * 64 + rt * 16 + quad * 4 + reg;  // token
          int gn = n0 + wc * 64 + ct * 16 + l16;             // feature
          int bb = gm >> 11, t = gm & 2047, hh = gn >> 6, dk = gn & 63;
          D[(((size_t)(bb * 8 + hh) * TT + t) << 6) + dk] = f2h(v);
        } else {
          int feat = n0 + wc * 64 + ct * 16 + quad * 4 + reg;
          int tok  = m0 + wr * 64 + rt * 16 + l16;
          int bb = tok >> 11, t = tok & 2047, hh = feat >> 6, dk = feat & 63;
          D[(((size_t)(bb * 8 + hh) << 6) + dk) * TT + t] = f2h(v);
        }
      }
}

// ---------------- output GEMM: out = y @ Wo^T, 64x128 tiles, fp32 out
__global__ __launch_bounds__(256) void k_ogemm(
    const u16* __restrict__ A, const u16* __restrict__ W,
    float* __restrict__ Df) {
  const int tid = threadIdx.x;
  const int wave = tid >> 6, lane = tid & 63;
  const int quad = lane >> 4, l16 = lane & 15;
  const int wr = wave >> 1, wc = wave & 1;
  const int m0 = blockIdx.x * 64, n0 = blockIdx.y * 128;

  __shared__ __align__(16) u16 As[64 * 64];
  __shared__ __align__(16) u16 Bs[128 * 64];

  f32x4 acc[2][4];
  for (int rt = 0; rt < 2; ++rt)
    for (int ct = 0; ct < 4; ++ct) acc[rt][ct] = (f32x4){0.f, 0.f, 0.f, 0.f};

  for (int kb = 0; kb < 8; ++kb) {
    const int k0 = kb * 64;
    for (int r = 0; r < 2; ++r) {
      int cid = r * 256 + tid;
      int row = cid >> 3, cl = cid & 7, cg = cl ^ (row & 7);
      async16(A + (size_t)(m0 + row) * DIM + k0 + cg * 8,
              &As[(r * 256 + wave * 64) * 8]);
    }
    for (int r = 0; r < 4; ++r) {
      int cid = r * 256 + tid;
      int row = cid >> 3, cl = cid & 7, cg = cl ^ (row & 7);
      async16(W + (size_t)(n0 + row) * DIM + k0 + cg * 8,
              &Bs[(r * 256 + wave * 64) * 8]);
    }
    __syncthreads();
    for (int kc = 0; kc < 2; ++kc) {
      half8 af[2], wf[4];
      for (int rt = 0; rt < 2; ++rt) {
        int row = wr * 32 + rt * 16 + l16;
        int c = (kc * 4 + quad) ^ (row & 7);
        af[rt] = *(const half8*)&As[row * 64 + c * 8];
      }
      for (int ct = 0; ct < 4; ++ct) {
        int row = wc * 64 + ct * 16 + l16;
        int c = (kc * 4 + quad) ^ (row & 7);
        wf[ct] = *(const half8*)&Bs[row * 64 + c * 8];
      }
      for (int rt = 0; rt < 2; ++rt)
        for (int ct = 0; ct < 4; ++ct)
          acc[rt][ct] = __builtin_amdgcn_mfma_f32_16x16x32_f16(
              af[rt], wf[ct], acc[rt][ct], 0, 0, 0);
    }
    __syncthreads();
  }

  for (int rt = 0; rt < 2; ++rt)
    for (int ct = 0; ct < 4; ++ct)
      for (int reg = 0; reg < 4; ++reg) {
        int gm = m0 + wr * 32 + rt * 16 + quad * 4 + reg;
        int gn = n0 + wc * 64 + ct * 16 + l16;
        Df[(size_t)gm * DIM + gn] = acc[rt][ct][reg];
      }
}

// ---------------- flash attention, single-buffered K/V, 2 barriers/iter.
// P transpose is intra-wave (wave wv writes & reads P rows [wv*16,wv*16+16)),
// so no barrier around the Pl round-trip. Bias/mask prefetched 1 tile ahead
// into statically-named register slots (A/B, loop unrolled x2).
// XCD swizzle: the 4 batches sharing a bias tile land at bx === same (mod 8).
__global__ __launch_bounds__(256, 4) void k_attn(
    const u16* __restrict__ Q, const u16* __restrict__ K,
    const u16* __restrict__ Vt, const float* __restrict__ bias,
    const float* __restrict__ mask, u16* __restrict__ Y) {
  const int tid = threadIdx.x;
  const int wv = tid >> 6;
  const int lane = tid & 63;
  const int quad = lane >> 4;
  const int l16 = lane & 15;

  const int bx = blockIdx.x;
  const int glo = bx & 7;
  const int b = (bx >> 3) & 3;
  const int g = ((bx >> 5) << 3) | glo;  // h*32 + qt, 0..255
  const int h = g >> 5, qt = g & 31;
  const int bh = b * 8 + h;
  const int q0 = qt * 64;

  __shared__ __align__(16) u16 Ks[64 * 64];  // K tile [s][dk]
  __shared__ __align__(16) u16 Vs[64 * 64];  // V^T tile [dk][s]
  __shared__ __align__(16) u16 Pl[64 * 72];  // P, padded stride 72

  // Q fragments (A-operand: m=lane&15, k=quad*8+j); wave wv owns rows wv*16..+15
  half8 qf[2];
  {
    size_t qrow = (size_t)bh * TT + q0 + wv * 16 + l16;
    for (int kc = 0; kc < 2; ++kc)
      qf[kc] = *(const half8*)(Q + qrow * 64 + kc * 32 + quad * 8);
  }

  const int tg = q0 + wv * 16 + quad * 4;
  const float* bb0 = bias + (size_t)h * TT * TT + (size_t)tg * TT + l16;
  const float* mbase = mask + (size_t)b * TT + l16;

  float m_i[4], l_i[4];
  f32x4 oacc[4];
  for (int r = 0; r < 4; ++r) { m_i[r] = -1e30f; l_i[r] = 0.f; }
  for (int ct = 0; ct < 4; ++ct) oacc[ct] = (f32x4){0.f, 0.f, 0.f, 0.f};

  float bvA[4][4], mkA[4], bvB[4][4], mkB[4];

  // Prologue: bias/mask tile 0 -> slot A; stage K/V tile 0.
  for (int reg = 0; reg < 4; ++reg)
    for (int ct = 0; ct < 4; ++ct)
      bvA[ct][reg] = bb0[(size_t)reg * TT + ct * 16];
  for (int ct = 0; ct < 4; ++ct) mkA[ct] = mbase[ct * 16];
  {
    for (int r = 0; r < 2; ++r) {
      int cid = r * 256 + tid;
      int row = cid >> 3, cl = cid & 7, cg = cl ^ (row & 7);
      async16(K + ((size_t)bh * TT + row) * 64 + cg * 8,
              &Ks[(r * 256 + wv * 64) * 8]);
      async16(Vt + ((size_t)(bh * 64 + row)) * TT + cg * 8,
              &Vs[(r * 256 + wv * 64) * 8]);
    }
  }
  __syncthreads();

#define AITER(ST, CB, CM, NB, NM)                                              \
  {                                                                            \
    const int st_ = (ST);                                                      \
    /* S = Q @ K^T */                                                          \
    f32x4 sacc[4];                                                             \
    for (int ct = 0; ct < 4; ++ct) sacc[ct] = (f32x4){0.f, 0.f, 0.f, 0.f};     \
    for (int kc = 0; kc < 2; ++kc) {                                           \
      half8 kf[4];                                                             \
      for (int ct = 0; ct < 4; ++ct) {                                         \
        int row = ct * 16 + l16;                                               \
        int c = (kc * 4 + quad) ^ (row & 7);                                   \
        kf[ct] = *(const half8*)&Ks[row * 64 + c * 8];                         \
      }                                                                        \
      for (int ct = 0; ct < 4; ++ct)                                           \
        sacc[ct] = __builtin_amdgcn_mfma_f32_16x16x32_f16(                     \
            qf[kc], kf[ct], sacc[ct], 0, 0, 0);                                \
    }                                                                          \
    /* prefetch bias/mask for st+1 into the other slot (VGPR loads, */         \
    /* consumed one full iteration later) */                                   \
    if (st_ < 31) {                                                            \
      const int s1 = (st_ + 1) * 64;                                           \
      for (int reg = 0; reg < 4; ++reg)                                        \
        for (int ct = 0; ct < 4; ++ct)                                         \
          NB[ct][reg] = bb0[(size_t)reg * TT + s1 + ct * 16];                  \
      for (int ct = 0; ct < 4; ++ct) NM[ct] = mbase[s1 + ct * 16];             \
    }                                                                          \
    /* online softmax; rows live in the 16 lanes of one quad */                \
    for (int reg = 0; reg < 4; ++reg) {                                        \
      float s[4];                                                              \
      for (int ct = 0; ct < 4; ++ct)                                           \
        s[ct] = sacc[ct][reg] + CB[ct][reg] + CM[ct];                          \
      float mx = fmaxf(fmaxf(s[0], s[1]), fmaxf(s[2], s[3]));                  \
      mx = fmaxf(mx, __shfl_xor(mx, 1));                                       \
      mx = fmaxf(mx, __shfl_xor(mx, 2));                                       \
      mx = fmaxf(mx, __shfl_xor(mx, 4));                                       \
      mx = fmaxf(mx, __shfl_xor(mx, 8));                                       \
      float mold = m_i[reg];                                                   \
      float mnew = fmaxf(mold, mx);                                            \
      float alpha = __builtin_amdgcn_exp2f((mold - mnew) * L2E);               \
      float p[4], rs = 0.f;                                                    \
      for (int ct = 0; ct < 4; ++ct) {                                         \
        p[ct] = __builtin_amdgcn_exp2f((s[ct] - mnew) * L2E);                  \
        rs += p[ct];                                                           \
      }                                                                        \
      rs += __shfl_xor(rs, 1);                                                 \
      rs += __shfl_xor(rs, 2);                                                 \
      rs += __shfl_xor(rs, 4);                                                 \
      rs += __shfl_xor(rs, 8);                                                 \
      l_i[reg] = l_i[reg] * alpha + rs;                                        \
      m_i[reg] = mnew;                                                         \
      for (int ct = 0; ct < 4; ++ct) oacc[ct][reg] *= alpha;                   \
      int prow = wv * 16 + quad * 4 + reg;                                     \
      for (int ct = 0; ct < 4; ++ct)                                           \
        Pl[prow * 72 + ct * 16 + l16] = f2h(p[ct]);                            \
    }                                                                          \
    /* O += P @ V : P rows are this wave's own writes (intra-wave, no */       \
    /* barrier; compiler emits lgkmcnt wait) */                                \
    for (int kc = 0; kc < 2; ++kc) {                                           \
      half8 pf, vf[4];                                                         \
      pf = *(const half8*)&Pl[(wv * 16 + l16) * 72 + kc * 32 + quad * 8];      \
      for (int ct = 0; ct < 4; ++ct) {                                         \
        int row = ct * 16 + l16;                                               \
        int c = (kc * 4 + quad) ^ (row & 7);                                   \
        vf[ct] = *(const half8*)&Vs[row * 64 + c * 8];                         \
      }                                                                        \
      for (int ct = 0; ct < 4; ++ct)                                           \
        oacc[ct] = __builtin_amdgcn_mfma_f32_16x16x32_f16(                     \
            pf, vf[ct], oacc[ct], 0, 0, 0);                                    \
    }                                                                          \
    __syncthreads(); /* all waves done reading Ks/Vs */                        \
    if (st_ < 31) {                                                            \
      const int s1 = (st_ + 1) * 64;                                           \
      for (int r = 0; r < 2; ++r) {                                            \
        int cid = r * 256 + tid;                                               \
        int row = cid >> 3, cl = cid & 7, cg = cl ^ (row & 7);                 \
        async16(K + ((size_t)bh * TT + s1 + row) * 64 + cg * 8,                \
                &Ks[(r * 256 + wv * 64) * 8]);                                 \
        async16(Vt + ((size_t)(bh * 64 + row)) * TT + s1 + cg * 8,             \
                &Vs[(r * 256 + wv * 64) * 8]);                                 \
      }                                                                        \
    }                                                                          \
    __syncthreads(); /* staged K/V visible (vmcnt drained here) */             \
  }

  for (int st2 = 0; st2 < 16; ++st2) {
    AITER(2 * st2, bvA, mkA, bvB, mkB);
    AITER(2 * st2 + 1, bvB, mkB, bvA, mkA);
  }
#undef AITER

  // Epilogue: y token-major [B,T,512] f16 (feeds the output GEMM).
  for (int reg = 0; reg < 4; ++reg) {
    int tgr = tg + reg;
    float inv = 1.f / l_i[reg];
    for (int ct = 0; ct < 4; ++ct) {
      float v = oacc[ct][reg] * inv;
      Y[((size_t)(b * TT + tgr)) * DIM + h * 64 + ct * 16 + l16] = f2h(v);
    }
  }
}

extern "C" void kernel_launch(void* const* d_in, const int* in_sizes, int n_in,
                              void* d_out, int out_size, void* d_ws, size_t ws_size,
                              hipStream_t stream) {
  const float* x    = (const float*)d_in[0];
  const float* mask = (const float*)d_in[1];
  const float* bias = (const float*)d_in[2];
  const float* Wq   = (const float*)d_in[3];
  const float* Wk   = (const float*)d_in[4];
  const float* Wv   = (const float*)d_in[5];
  const float* Wo   = (const float*)d_in[6];
  (void)Wk; (void)Wv;  // consumed via contiguous weight block in ws

  // Workspace (f16 elems): xb | wq,wk,wv,wo | Q,K,Vt | y  (~44 MB)
  u16* xb  = (u16*)d_ws;
  u16* wb  = xb + 4194304;            // 4 * 262144
  u16* qkv = wb + 4 * 262144;         // Q, K head-major; V^T
  u16* yb  = qkv + 3 * (size_t)4194304;

  k_convert<<<2560, 256, 0, stream>>>(x, Wq, Wk, Wv, Wo, xb);
  k_proj<<<dim3(64, 12), 256, 0, stream>>>(xb, wb, qkv);
  k_attn<<<1024, 256, 0, stream>>>(qkv, qkv + 4194304,
                                   qkv + 2 * (size_t)4194304, bias, mask, yb);
  k_ogemm<<<dim3(128, 4), 256, 0, stream>>>(yb, wb + 3 * 262144, (float*)d_out);
}

// Round 6
// 343.005 us; speedup vs baseline: 1.5447x; 1.4558x over previous
//
#include <hip/hip_runtime.h>
#include <stdint.h>

typedef unsigned short u16;
typedef __attribute__((ext_vector_type(8))) _Float16 half8;  // 8 x f16 (4 VGPRs)
typedef __attribute__((ext_vector_type(4))) float f32x4;

#define L2E 1.4426950408889634f

// B=4, T=2048, D=512, H=8, DK=64; NTOK = B*T = 8192
#define NTOK 8192
#define DIM  512
#define TT   2048

__device__ __forceinline__ u16 f2h(float f) {
  _Float16 h = (_Float16)f;  // RNE via v_cvt_f16_f32
  return __builtin_bit_cast(u16, h);
}

__device__ __forceinline__ void async16(const void* g, void* l) {
  __builtin_amdgcn_global_load_lds(
      (const __attribute__((address_space(1))) unsigned int*)g,
      (__attribute__((address_space(3))) unsigned int*)l, 16, 0, 0);
}

// ---------------- fp32 -> fp16 conversion: x (4.19M) + 4 weights (262144 each)
__global__ __launch_bounds__(256) void k_convert(
    const float* __restrict__ x, const float* __restrict__ wq,
    const float* __restrict__ wk, const float* __restrict__ wv,
    const float* __restrict__ wo, u16* __restrict__ xb) {
  size_t i = ((size_t)blockIdx.x * 256 + threadIdx.x) * 8;
  const float* src;
  u16* dst;
  size_t off;
  if (i < 4194304) {
    src = x; dst = xb; off = i;
  } else {
    size_t j = i - 4194304;
    int w = (int)(j >> 18);
    off = j & 262143;
    src = (w == 0) ? wq : (w == 1) ? wk : (w == 2) ? wv : wo;
    dst = xb + 4194304 + (size_t)w * 262144;
  }
  float4 a = *(const float4*)(src + off);
  float4 b = *(const float4*)(src + off + 4);
  uint4 pk;
  pk.x = (unsigned)f2h(a.x) | ((unsigned)f2h(a.y) << 16);
  pk.y = (unsigned)f2h(a.z) | ((unsigned)f2h(a.w) << 16);
  pk.z = (unsigned)f2h(b.x) | ((unsigned)f2h(b.y) << 16);
  pk.w = (unsigned)f2h(b.z) | ((unsigned)f2h(b.w) << 16);
  *(uint4*)(dst + off) = pk;
}

// ---------------- merged QKV projection: grid (64, 24), 128x64 tiles
// n-tiles span stacked [Wq;Wk;Wv] (1536 rows). z = n0g/512 selects output.
// z<2 (Q,K): head-major [bh][t][dk]. z==2 (V): swapped MFMA operands ->
// transposed Vt [bh][dk][t] with coalesced stores.
__global__ __launch_bounds__(256) void k_proj(
    const u16* __restrict__ A, const u16* __restrict__ Wall,
    u16* __restrict__ Db) {
  const int tid = threadIdx.x;
  const int wave = tid >> 6, lane = tid & 63;
  const int quad = lane >> 4, l16 = lane & 15;
  const int m0 = blockIdx.x * 128;
  const int n0g = blockIdx.y * 64;       // 0..1536
  const int z = n0g >> 9;                // 0,1,2 (block-uniform)
  const int n0 = n0g & 511;

  const u16* W = Wall + (size_t)n0g * DIM;
  u16* D = Db + (size_t)z * 4194304;

  __shared__ __align__(16) u16 As[128 * 64];
  __shared__ __align__(16) u16 Bs[64 * 64];

  f32x4 acc[2][4];
  for (int rt = 0; rt < 2; ++rt)
    for (int ct = 0; ct < 4; ++ct) acc[rt][ct] = (f32x4){0.f, 0.f, 0.f, 0.f};

  for (int kb = 0; kb < 8; ++kb) {
    const int k0 = kb * 64;
    for (int r = 0; r < 4; ++r) {
      int cid = r * 256 + tid;
      int row = cid >> 3, cl = cid & 7, cg = cl ^ (row & 7);
      async16(A + (size_t)(m0 + row) * DIM + k0 + cg * 8,
              &As[(r * 256 + wave * 64) * 8]);
    }
    for (int r = 0; r < 2; ++r) {
      int cid = r * 256 + tid;
      int row = cid >> 3, cl = cid & 7, cg = cl ^ (row & 7);
      async16(W + (size_t)row * DIM + k0 + cg * 8,
              &Bs[(r * 256 + wave * 64) * 8]);
    }
    __syncthreads();
    for (int kc = 0; kc < 2; ++kc) {
      half8 af[2], wf[4];
      for (int rt = 0; rt < 2; ++rt) {
        int row = wave * 32 + rt * 16 + l16;
        int c = (kc * 4 + quad) ^ (row & 7);
        af[rt] = *(const half8*)&As[row * 64 + c * 8];
      }
      for (int ct = 0; ct < 4; ++ct) {
        int row = ct * 16 + l16;
        int c = (kc * 4 + quad) ^ (row & 7);
        wf[ct] = *(const half8*)&Bs[row * 64 + c * 8];
      }
      if (z != 2) {
        for (int rt = 0; rt < 2; ++rt)
          for (int ct = 0; ct < 4; ++ct)
            acc[rt][ct] = __builtin_amdgcn_mfma_f32_16x16x32_f16(
                af[rt], wf[ct], acc[rt][ct], 0, 0, 0);
      } else {
        for (int rt = 0; rt < 2; ++rt)
          for (int ct = 0; ct < 4; ++ct)
            acc[rt][ct] = __builtin_amdgcn_mfma_f32_16x16x32_f16(
                wf[ct], af[rt], acc[rt][ct], 0, 0, 0);
      }
    }
    __syncthreads();
  }

  // C/D layout: col = lane&15, row = quad*4 + reg.
  for (int rt = 0; rt < 2; ++rt)
    for (int ct = 0; ct < 4; ++ct)
      for (int reg = 0; reg < 4; ++reg) {
        float v = acc[rt][ct][reg];
        if (z != 2) {
          int gm = m0 + wave * 32 + rt * 16 + quad * 4 + reg;  // token
          int gn = n0 + ct * 16 + l16;                         // feature
          int bb = gm >> 11, t = gm & 2047, hh = gn >> 6, dk = gn & 63;
          D[(((size_t)(bb * 8 + hh) * TT + t) << 6) + dk] = f2h(v);
        } else {
          int feat = n0 + ct * 16 + quad * 4 + reg;
          int tok  = m0 + wave * 32 + rt * 16 + l16;
          int bb = tok >> 11, t = tok & 2047, hh = feat >> 6, dk = feat & 63;
          D[(((size_t)(bb * 8 + hh) << 6) + dk) * TT + t] = f2h(v);
        }
      }
}

// ---------------- output GEMM: out = y @ Wo^T, 64x64 tiles, fp32 out
__global__ __launch_bounds__(256) void k_ogemm(
    const u16* __restrict__ A, const u16* __restrict__ W,
    float* __restrict__ Df) {
  const int tid = threadIdx.x;
  const int wave = tid >> 6, lane = tid & 63;
  const int quad = lane >> 4, l16 = lane & 15;
  const int m0 = blockIdx.x * 64, n0 = blockIdx.y * 64;

  __shared__ __align__(16) u16 As[64 * 64];
  __shared__ __align__(16) u16 Bs[64 * 64];

  f32x4 acc[4];
  for (int ct = 0; ct < 4; ++ct) acc[ct] = (f32x4){0.f, 0.f, 0.f, 0.f};

  for (int kb = 0; kb < 8; ++kb) {
    const int k0 = kb * 64;
    for (int r = 0; r < 2; ++r) {
      int cid = r * 256 + tid;
      int row = cid >> 3, cl = cid & 7, cg = cl ^ (row & 7);
      async16(A + (size_t)(m0 + row) * DIM + k0 + cg * 8,
              &As[(r * 256 + wave * 64) * 8]);
    }
    for (int r = 0; r < 2; ++r) {
      int cid = r * 256 + tid;
      int row = cid >> 3, cl = cid & 7, cg = cl ^ (row & 7);
      async16(W + (size_t)(n0 + row) * DIM + k0 + cg * 8,
              &Bs[(r * 256 + wave * 64) * 8]);
    }
    __syncthreads();
    for (int kc = 0; kc < 2; ++kc) {
      half8 af, wf[4];
      {
        int row = wave * 16 + l16;
        int c = (kc * 4 + quad) ^ (row & 7);
        af = *(const half8*)&As[row * 64 + c * 8];
      }
      for (int ct = 0; ct < 4; ++ct) {
        int row = ct * 16 + l16;
        int c = (kc * 4 + quad) ^ (row & 7);
        wf[ct] = *(const half8*)&Bs[row * 64 + c * 8];
      }
      for (int ct = 0; ct < 4; ++ct)
        acc[ct] = __builtin_amdgcn_mfma_f32_16x16x32_f16(
            af, wf[ct], acc[ct], 0, 0, 0);
    }
    __syncthreads();
  }

  for (int ct = 0; ct < 4; ++ct)
    for (int reg = 0; reg < 4; ++reg) {
      int gm = m0 + wave * 16 + quad * 4 + reg;
      int gn = n0 + ct * 16 + l16;
      Df[(size_t)gm * DIM + gn] = acc[ct][reg];
    }
}

// ---------------- flash attention: 1024 blocks, bx = qt*32 + b*8 + h
// => XCD (bx%8) = h: each head's bias (16.8 MB) + K/V (2 MB) pinned to one
// XCD's L2; the 4 batch-sharers of a bias tile are co-resident there.
// Single K/V buffer, 2 barriers/iter (P round-trip is intra-wave).
// Q prescaled by log2(e); bias/mask prefetched 1 tile ahead (raw loads only;
// the (bv+mk)*L2E fold happens at consume as 2 FMAs).
__global__ __launch_bounds__(256) void k_attn(
    const u16* __restrict__ Q, const u16* __restrict__ K,
    const u16* __restrict__ Vt, const float* __restrict__ bias,
    const float* __restrict__ mask, u16* __restrict__ Y) {
  const int tid = threadIdx.x;
  const int wv = tid >> 6;
  const int lane = tid & 63;
  const int quad = lane >> 4;
  const int l16 = lane & 15;

  const int bx = blockIdx.x;
  const int h = bx & 7;
  const int b = (bx >> 3) & 3;
  const int qt = bx >> 5;  // 0..31
  const int bh = b * 8 + h;
  const int q0 = qt * 64;

  __shared__ __align__(16) u16 Ks[64 * 64];  // K tile [s][dk]
  __shared__ __align__(16) u16 Vs[64 * 64];  // V^T tile [dk][s]
  __shared__ __align__(16) u16 Pl[64 * 72];  // P, padded stride 72

  // Q fragments (A-operand: m=lane&15, k=quad*8+j), prescaled by log2(e).
  half8 qf[2];
  {
    size_t qrow = (size_t)bh * TT + q0 + wv * 16 + l16;
    for (int kc = 0; kc < 2; ++kc) {
      qf[kc] = *(const half8*)(Q + qrow * 64 + kc * 32 + quad * 8);
      qf[kc] = qf[kc] * (_Float16)L2E;
    }
  }

  const int tg = q0 + wv * 16 + quad * 4;
  const float* bb0 = bias + (size_t)h * TT * TT + (size_t)tg * TT + l16;
  const float* mbase = mask + (size_t)b * TT + l16;

  float m_i[4], l_lane[4];
  f32x4 oacc[4];
  for (int r = 0; r < 4; ++r) { m_i[r] = -1e30f; l_lane[r] = 0.f; }
  for (int ct = 0; ct < 4; ++ct) oacc[ct] = (f32x4){0.f, 0.f, 0.f, 0.f};

  float bvN[4][4], mkN[4], bvC[4][4], mkC[4];

  // Prologue: bias/mask tile 0 -> N slots; stage K/V tile 0.
  for (int reg = 0; reg < 4; ++reg)
    for (int ct = 0; ct < 4; ++ct)
      bvN[ct][reg] = bb0[(size_t)reg * TT + ct * 16];
  for (int ct = 0; ct < 4; ++ct) mkN[ct] = mbase[ct * 16];
  for (int r = 0; r < 2; ++r) {
    int cid = r * 256 + tid;
    int row = cid >> 3, cl = cid & 7, cg = cl ^ (row & 7);
    async16(K + ((size_t)bh * TT + row) * 64 + cg * 8,
            &Ks[(r * 256 + wv * 64) * 8]);
    async16(Vt + ((size_t)(bh * 64 + row)) * TT + cg * 8,
            &Vs[(r * 256 + wv * 64) * 8]);
  }
  __syncthreads();

  for (int st = 0; st < 32; ++st) {
    // Rotate prefetch slots; issue next tile's bias/mask loads (pure VMEM,
    // results consumed next iteration -> latency hidden by this iteration).
    for (int reg = 0; reg < 4; ++reg)
      for (int ct = 0; ct < 4; ++ct) bvC[ct][reg] = bvN[ct][reg];
    for (int ct = 0; ct < 4; ++ct) mkC[ct] = mkN[ct];
    if (st < 31) {
      const int s1 = (st + 1) * 64;
      for (int reg = 0; reg < 4; ++reg)
        for (int ct = 0; ct < 4; ++ct)
          bvN[ct][reg] = bb0[(size_t)reg * TT + s1 + ct * 16];
      for (int ct = 0; ct < 4; ++ct) mkN[ct] = mbase[s1 + ct * 16];
    }

    // S = Q @ K^T (already in exp2 domain via Q prescale).
    f32x4 sacc[4];
    for (int ct = 0; ct < 4; ++ct) sacc[ct] = (f32x4){0.f, 0.f, 0.f, 0.f};
    for (int kc = 0; kc < 2; ++kc) {
      half8 kf[4];
      for (int ct = 0; ct < 4; ++ct) {
        int row = ct * 16 + l16;
        int c = (kc * 4 + quad) ^ (row & 7);
        kf[ct] = *(const half8*)&Ks[row * 64 + c * 8];
      }
      for (int ct = 0; ct < 4; ++ct)
        sacc[ct] = __builtin_amdgcn_mfma_f32_16x16x32_f16(
            qf[kc], kf[ct], sacc[ct], 0, 0, 0);
    }

    // Online softmax (exp2 domain). Row = 16 lanes of one quad.
    // l-sum deferred: per-lane partials, reduced once at epilogue
    // (alpha is row-uniform, so per-lane rescale is consistent).
    for (int reg = 0; reg < 4; ++reg) {
      float s[4];
      for (int ct = 0; ct < 4; ++ct) {
        float t = __builtin_fmaf(mkC[ct], L2E, sacc[ct][reg]);
        s[ct] = __builtin_fmaf(bvC[ct][reg], L2E, t);
      }
      float mx = fmaxf(fmaxf(s[0], s[1]), fmaxf(s[2], s[3]));
      mx = fmaxf(mx, __shfl_xor(mx, 1));
      mx = fmaxf(mx, __shfl_xor(mx, 2));
      mx = fmaxf(mx, __shfl_xor(mx, 4));
      mx = fmaxf(mx, __shfl_xor(mx, 8));
      float mold = m_i[reg];
      float mnew = fmaxf(mold, mx);
      float alpha = __builtin_amdgcn_exp2f(mold - mnew);
      float p[4], rs = 0.f;
      for (int ct = 0; ct < 4; ++ct) {
        p[ct] = __builtin_amdgcn_exp2f(s[ct] - mnew);
        rs += p[ct];
      }
      l_lane[reg] = __builtin_fmaf(l_lane[reg], alpha, rs);
      m_i[reg] = mnew;
      for (int ct = 0; ct < 4; ++ct) oacc[ct][reg] *= alpha;
      int prow = wv * 16 + quad * 4 + reg;
      for (int ct = 0; ct < 4; ++ct)
        Pl[prow * 72 + ct * 16 + l16] = f2h(p[ct]);
    }

    // O += P @ V. P rows are this wave's own writes (intra-wave; the
    // compiler's lgkmcnt wait orders the LDS round-trip, no barrier).
    for (int kc = 0; kc < 2; ++kc) {
      half8 pf, vf[4];
      pf = *(const half8*)&Pl[(wv * 16 + l16) * 72 + kc * 32 + quad * 8];
      for (int ct = 0; ct < 4; ++ct) {
        int row = ct * 16 + l16;
        int c = (kc * 4 + quad) ^ (row & 7);
        vf[ct] = *(const half8*)&Vs[row * 64 + c * 8];
      }
      for (int ct = 0; ct < 4; ++ct)
        oacc[ct] = __builtin_amdgcn_mfma_f32_16x16x32_f16(
            pf, vf[ct], oacc[ct], 0, 0, 0);
    }

    __syncthreads();  // all waves done reading Ks/Vs
    if (st < 31) {
      const int s1 = (st + 1) * 64;
      for (int r = 0; r < 2; ++r) {
        int cid = r * 256 + tid;
        int row = cid >> 3, cl = cid & 7, cg = cl ^ (row & 7);
        async16(K + ((size_t)bh * TT + s1 + row) * 64 + cg * 8,
                &Ks[(r * 256 + wv * 64) * 8]);
        async16(Vt + ((size_t)(bh * 64 + row)) * TT + s1 + cg * 8,
                &Vs[(r * 256 + wv * 64) * 8]);
      }
    }
    __syncthreads();  // staged K/V visible
  }

  // Epilogue: reduce l across the 16-lane row, then y token-major f16.
  for (int reg = 0; reg < 4; ++reg) {
    float l = l_lane[reg];
    l += __shfl_xor(l, 1);
    l += __shfl_xor(l, 2);
    l += __shfl_xor(l, 4);
    l += __shfl_xor(l, 8);
    float inv = 1.f / l;
    int tgr = tg + reg;
    for (int ct = 0; ct < 4; ++ct) {
      float v = oacc[ct][reg] * inv;
      Y[((size_t)(b * TT + tgr)) * DIM + h * 64 + ct * 16 + l16] = f2h(v);
    }
  }
}

extern "C" void kernel_launch(void* const* d_in, const int* in_sizes, int n_in,
                              void* d_out, int out_size, void* d_ws, size_t ws_size,
                              hipStream_t stream) {
  const float* x    = (const float*)d_in[0];
  const float* mask = (const float*)d_in[1];
  const float* bias = (const float*)d_in[2];
  const float* Wq   = (const float*)d_in[3];
  const float* Wk   = (const float*)d_in[4];
  const float* Wv   = (const float*)d_in[5];
  const float* Wo   = (const float*)d_in[6];
  (void)Wk; (void)Wv;  // consumed via contiguous weight block in ws

  // Workspace (f16 elems): xb | wq,wk,wv,wo | Q,K,Vt | y  (~44 MB)
  u16* xb  = (u16*)d_ws;
  u16* wb  = xb + 4194304;            // 4 * 262144
  u16* qkv = wb + 4 * 262144;         // Q, K head-major; V^T
  u16* yb  = qkv + 3 * (size_t)4194304;

  k_convert<<<2560, 256, 0, stream>>>(x, Wq, Wk, Wv, Wo, xb);
  k_proj<<<dim3(64, 24), 256, 0, stream>>>(xb, wb, qkv);
  k_attn<<<1024, 256, 0, stream>>>(qkv, qkv + 4194304,
                                   qkv + 2 * (size_t)4194304, bias, mask, yb);
  k_ogemm<<<dim3(128, 8), 256, 0, stream>>>(yb, wb + 3 * 262144, (float*)d_out);
}